// Round 1
// baseline (168.429 us; speedup 1.0000x reference)
//
#include <hip/hip_runtime.h>

// Problem constants (fixed by setup_inputs)
#define B_ 8
#define N_ 16384
#define C_ 64
#define S_ 5

typedef float v4f __attribute__((ext_vector_type(4)));
typedef __bf16 v8bf __attribute__((ext_vector_type(8)));
typedef unsigned int v4u __attribute__((ext_vector_type(4)));

// fp32 -> bf16 bits, round-to-nearest-even (finite inputs only)
static __device__ __forceinline__ unsigned short f2bf(float f) {
    unsigned int u = __float_as_uint(f);
    u += 0x7fffu + ((u >> 16) & 1u);
    return (unsigned short)(u >> 16);
}
static __device__ __forceinline__ float bf2f(unsigned short s) {
    return __uint_as_float(((unsigned int)s) << 16);
}

// ---------------------------------------------------------------------------
// Kernel 1: farthest point sampling. One block per batch; dists+xyz live in
// registers (512 thr x 32 pts). Matches jax scan semantics: idx[0]=0, then
// idx[k] = argmax (FIRST max index) of running min-distance.
// ---------------------------------------------------------------------------
__global__ __launch_bounds__(512) void fps_kernel(const float* __restrict__ xyz,
                                                  int* __restrict__ idx_out) {
    const int b = blockIdx.x;
    const float* p = xyz + (size_t)b * N_ * 3;
    const int t = threadIdx.x;
    const int PPT = N_ / 512; // 32

    float px[PPT], py[PPT], pz[PPT], dist[PPT];
#pragma unroll
    for (int k = 0; k < PPT; ++k) {
        int i = t + k * 512;
        px[k] = p[i * 3 + 0];
        py[k] = p[i * 3 + 1];
        pz[k] = p[i * 3 + 2];
        dist[k] = 1e10f;
    }

    __shared__ float s_best[8];
    __shared__ int s_bidx[8];
    __shared__ int s_last;
    int last = 0;
    if (t == 0) idx_out[b * S_ + 0] = 0;

    for (int step = 1; step < S_; ++step) {
        const float lx = p[last * 3 + 0];
        const float ly = p[last * 3 + 1];
        const float lz = p[last * 3 + 2];
        float best = -1.0f;
        int bidx = 0;
#pragma unroll
        for (int k = 0; k < PPT; ++k) {
            float dx = px[k] - lx, dy = py[k] - ly, dz = pz[k] - lz;
            float d = dx * dx + dy * dy + dz * dz;
            float nd = fminf(dist[k], d);
            dist[k] = nd;
            // strict > keeps the lowest index within this thread (i increases)
            if (nd > best) { best = nd; bidx = t + k * 512; }
        }
        // wave(64) reduction, tie -> smaller index (jnp.argmax: first max)
#pragma unroll
        for (int off = 32; off > 0; off >>= 1) {
            float ob = __shfl_down(best, off, 64);
            int oi = __shfl_down(bidx, off, 64);
            if (ob > best || (ob == best && oi < bidx)) { best = ob; bidx = oi; }
        }
        if ((t & 63) == 0) { s_best[t >> 6] = best; s_bidx[t >> 6] = bidx; }
        __syncthreads();
        if (t == 0) {
            float bb = s_best[0];
            int bi = s_bidx[0];
#pragma unroll
            for (int w = 1; w < 8; ++w) {
                if (s_best[w] > bb || (s_best[w] == bb && s_bidx[w] < bi)) {
                    bb = s_best[w];
                    bi = s_bidx[w];
                }
            }
            s_last = bi;
            idx_out[b * S_ + step] = bi;
        }
        __syncthreads();
        last = s_last;
        __syncthreads(); // protect s_best from next-iteration overwrite
    }
}

// ---------------------------------------------------------------------------
// Kernel 2: weight prep. Folds BN scale s = g*rsqrt(v+1e-5) into the weights:
//   Wa' = s1 .* W1[:, :64]        (bf16, for U used by slices s>=1)
//   Wc' = s1 .* (W1a + W1b)       (bf16, slice s=0 input is [fg;fg])
//   W2' = s2 .* W2                (bf16)
//   w1bs = s1 .* W1[:, 64:]       (fp32, for the per-sample constant vectors)
//   bb1 = b1 - m1*s1, bb2 = b2 - m2*s2
// ---------------------------------------------------------------------------
__global__ __launch_bounds__(256) void prep_w(
    const float* __restrict__ w1, const float* __restrict__ g1, const float* __restrict__ b1,
    const float* __restrict__ m1, const float* __restrict__ v1,
    const float* __restrict__ w2, const float* __restrict__ g2, const float* __restrict__ b2,
    const float* __restrict__ m2, const float* __restrict__ v2,
    float* __restrict__ w1bs, float* __restrict__ bb1, float* __restrict__ bb2,
    unsigned short* __restrict__ wa_bf, unsigned short* __restrict__ wc_bf,
    unsigned short* __restrict__ w2_bf) {
    const int t = threadIdx.x;
    for (int i = t; i < 64 * 64; i += 256) {
        const int o = i >> 6, c = i & 63;
        const float s1 = g1[o] / sqrtf(v1[o] + 1e-5f);
        const float s2 = g2[o] / sqrtf(v2[o] + 1e-5f);
        const float a = s1 * w1[o * 128 + c];
        const float bb = s1 * w1[o * 128 + 64 + c];
        w1bs[o * 64 + c] = bb;
        wa_bf[o * 64 + c] = f2bf(a);
        wc_bf[o * 64 + c] = f2bf(a + bb);
        w2_bf[o * 64 + c] = f2bf(s2 * w2[o * 64 + c]);
    }
    if (t < 64) {
        const float s1 = g1[t] / sqrtf(v1[t] + 1e-5f);
        const float s2 = g2[t] / sqrtf(v2[t] + 1e-5f);
        bb1[t] = b1[t] - m1[t] * s1;
        bb2[t] = b2[t] - m2[t] * s2;
    }
}

// ---------------------------------------------------------------------------
// Kernel 3: gather sampled bg features and build per-(b,sample) constants:
//   sbg[b][j][c] = bg_features[b, c, idx[b,j]]            (final multiplier)
//   ebb[b][j][o] = sum_c w1bs[o,c]*sbg[b,j,c] + bb1[o]    (layer-1 constant)
// ---------------------------------------------------------------------------
__global__ __launch_bounds__(64) void prep_sbg(
    const float* __restrict__ bg_feat, const int* __restrict__ idx,
    const float* __restrict__ w1bs, const float* __restrict__ bb1,
    float* __restrict__ sbg, float* __restrict__ ebb) {
    const int b = blockIdx.x, j = blockIdx.y;
    const int o = threadIdx.x;
    const int id = idx[b * S_ + j];
    __shared__ float sf[64];
    sf[o] = bg_feat[(size_t)b * C_ * N_ + (size_t)o * N_ + id];
    __syncthreads();
    float acc = 0.f;
#pragma unroll
    for (int c = 0; c < 64; ++c) acc += w1bs[o * 64 + c] * sf[c];
    sbg[(b * S_ + j) * 64 + o] = sf[o];
    ebb[(b * S_ + j) * 64 + o] = acc + bb1[o];
}

// ---------------------------------------------------------------------------
// Kernel 4: main fused MLP. One block = one batch x 64-column tile.
// LDS: Ft[n][c] (F transposed, bf16, pitch 72 shorts -> 16B-aligned rows,
// balanced bank distribution for the mfma b128 frag reads), Ht ditto for H.
// Per wave (4 waves): o-rows [16w,16w+16) x all 64 n.
//   GEMM1: U = Wa'.F, U0 = Wc'.F           (16x16x32 bf16 MFMA, 2 k-steps)
//   per slice s: H = relu(U(0) + const) -> Ht -> GEMM2 p = W2'.H
//                acc += relu(p + bb2) * (s==0 ? F : sbg)
// MFMA layouts (HW-verified): A[m=lane&15][k=(lane>>4)*8+j];
// C/D: col=lane&15, row=(lane>>4)*4+reg.
// ---------------------------------------------------------------------------
#define PITCH 72 // shorts per LDS row (36 words)

__global__ __launch_bounds__(256) void fusion_main(
    const float* __restrict__ fg_feat,
    const unsigned short* __restrict__ wa_bf, const unsigned short* __restrict__ wc_bf,
    const unsigned short* __restrict__ w2_bf,
    const float* __restrict__ bb1, const float* __restrict__ bb2,
    const float* __restrict__ ebb, const float* __restrict__ sbg,
    float* __restrict__ out) {
    __shared__ unsigned short Ft[64 * PITCH];
    __shared__ unsigned short Ht[64 * PITCH];

    const int t = threadIdx.x;
    const int b = blockIdx.y;
    const int n0 = blockIdx.x * 64;
    const float* Fg = fg_feat + (size_t)b * C_ * N_ + n0;

    // ---- stage F tile transposed (bf16) into Ft[n][c] ----
    {
        const int n = t & 63;
        const int cg = (t >> 6) * 16;
        v4u w0, w1v;
#pragma unroll
        for (int i = 0; i < 8; ++i) {
            unsigned short lo = f2bf(Fg[(size_t)(cg + 2 * i) * N_ + n]);
            unsigned short hi = f2bf(Fg[(size_t)(cg + 2 * i + 1) * N_ + n]);
            unsigned int packed = (unsigned int)lo | ((unsigned int)hi << 16);
            if (i < 4) w0[i] = packed; else w1v[i - 4] = packed;
        }
        *(v4u*)&Ft[n * PITCH + cg] = w0;
        *(v4u*)&Ft[n * PITCH + cg + 8] = w1v;
    }

    const int lane = t & 63;
    const int wv = t >> 6;     // wave id -> o-block
    const int o0 = wv * 16;
    const int m = lane & 15;   // A row / B col / D col
    const int q = lane >> 4;   // k-chunk / D row-group
    const int arow = o0 + m;

    // A-fragments straight from global (small, L2-resident)
    v8bf aWa[2], aWc[2], aW2[2];
#pragma unroll
    for (int ks = 0; ks < 2; ++ks) {
        aWa[ks] = *(const v8bf*)&wa_bf[arow * 64 + ks * 32 + q * 8];
        aWc[ks] = *(const v8bf*)&wc_bf[arow * 64 + ks * 32 + q * 8];
        aW2[ks] = *(const v8bf*)&w2_bf[arow * 64 + ks * 32 + q * 8];
    }

    // per-lane o-range constants (o = ob4 + reg)
    const int ob4 = o0 + 4 * q;
    const v4f bb1r = *(const v4f*)&bb1[ob4];
    const v4f bb2r = *(const v4f*)&bb2[ob4];
    v4f ebbr[5], sbgr[5];
#pragma unroll
    for (int j = 0; j < 5; ++j) {
        ebbr[j] = *(const v4f*)&ebb[(b * 5 + j) * 64 + ob4];
        sbgr[j] = *(const v4f*)&sbg[(b * 5 + j) * 64 + ob4];
    }

    __syncthreads(); // Ft ready

    // B-fragments of F
    v8bf bF[4][2];
#pragma unroll
    for (int nb = 0; nb < 4; ++nb)
#pragma unroll
        for (int ks = 0; ks < 2; ++ks)
            bF[nb][ks] = *(const v8bf*)&Ft[(nb * 16 + m) * PITCH + ks * 32 + q * 8];

    // GEMM1
    v4f U[4], U0[4];
#pragma unroll
    for (int nb = 0; nb < 4; ++nb) {
        v4f z = {0.f, 0.f, 0.f, 0.f};
        z = __builtin_amdgcn_mfma_f32_16x16x32_bf16(aWa[0], bF[nb][0], z, 0, 0, 0);
        U[nb] = __builtin_amdgcn_mfma_f32_16x16x32_bf16(aWa[1], bF[nb][1], z, 0, 0, 0);
        v4f z2 = {0.f, 0.f, 0.f, 0.f};
        z2 = __builtin_amdgcn_mfma_f32_16x16x32_bf16(aWc[0], bF[nb][0], z2, 0, 0, 0);
        U0[nb] = __builtin_amdgcn_mfma_f32_16x16x32_bf16(aWc[1], bF[nb][1], z2, 0, 0, 0);
    }

    v4f acc[4];
#pragma unroll
    for (int nb = 0; nb < 4; ++nb) acc[nb] = (v4f){0.f, 0.f, 0.f, 0.f};

#pragma unroll
    for (int s = 0; s < 6; ++s) {
        // form H (C-layout) and write transposed to Ht[n][c]
#pragma unroll
        for (int nb = 0; nb < 4; ++nb) {
            unsigned int lo, hi;
            {
                float h0 = (s == 0) ? (U0[nb][0] + bb1r[0]) : (U[nb][0] + ebbr[s - 1][0]);
                float h1 = (s == 0) ? (U0[nb][1] + bb1r[1]) : (U[nb][1] + ebbr[s - 1][1]);
                float h2 = (s == 0) ? (U0[nb][2] + bb1r[2]) : (U[nb][2] + ebbr[s - 1][2]);
                float h3 = (s == 0) ? (U0[nb][3] + bb1r[3]) : (U[nb][3] + ebbr[s - 1][3]);
                lo = (unsigned int)f2bf(fmaxf(h0, 0.f)) | ((unsigned int)f2bf(fmaxf(h1, 0.f)) << 16);
                hi = (unsigned int)f2bf(fmaxf(h2, 0.f)) | ((unsigned int)f2bf(fmaxf(h3, 0.f)) << 16);
            }
            unsigned long long v = (unsigned long long)lo | ((unsigned long long)hi << 32);
            *(unsigned long long*)&Ht[(nb * 16 + m) * PITCH + ob4] = v;
        }
        __syncthreads(); // Ht ready

        // GEMM2
        v4f p[4];
#pragma unroll
        for (int nb = 0; nb < 4; ++nb) {
            v8bf h0 = *(const v8bf*)&Ht[(nb * 16 + m) * PITCH + q * 8];
            v8bf h1 = *(const v8bf*)&Ht[(nb * 16 + m) * PITCH + 32 + q * 8];
            v4f z = {0.f, 0.f, 0.f, 0.f};
            z = __builtin_amdgcn_mfma_f32_16x16x32_bf16(aW2[0], h0, z, 0, 0, 0);
            p[nb] = __builtin_amdgcn_mfma_f32_16x16x32_bf16(aW2[1], h1, z, 0, 0, 0);
        }
        __syncthreads(); // Ht consumed before next slice overwrites

        // epilogue: acc += relu(p + bb2) * multiplier
#pragma unroll
        for (int nb = 0; nb < 4; ++nb) {
            if (s == 0) {
                unsigned long long fv = *(const unsigned long long*)&Ft[(nb * 16 + m) * PITCH + ob4];
#pragma unroll
                for (int r = 0; r < 4; ++r) {
                    float w = fmaxf(p[nb][r] + bb2r[r], 0.f);
                    acc[nb][r] += w * bf2f((unsigned short)(fv >> (16 * r)));
                }
            } else {
#pragma unroll
                for (int r = 0; r < 4; ++r) {
                    float w = fmaxf(p[nb][r] + bb2r[r], 0.f);
                    acc[nb][r] += w * sbgr[s - 1][r];
                }
            }
        }
    }

    // store: out[b][c][n], c = ob4+r, n = n0 + nb*16 + m
#pragma unroll
    for (int nb = 0; nb < 4; ++nb)
#pragma unroll
        for (int r = 0; r < 4; ++r)
            out[(size_t)b * C_ * N_ + (size_t)(ob4 + r) * N_ + (n0 + nb * 16 + m)] = acc[nb][r];
}

// ---------------------------------------------------------------------------
extern "C" void kernel_launch(void* const* d_in, const int* in_sizes, int n_in,
                              void* d_out, int out_size, void* d_ws, size_t ws_size,
                              hipStream_t stream) {
    const float* fg_xyz = (const float*)d_in[0];
    const float* fg_feat = (const float*)d_in[1];
    const float* bg_xyz = (const float*)d_in[2];
    const float* bg_feat = (const float*)d_in[3];
    const float* w1 = (const float*)d_in[4];
    const float* g1 = (const float*)d_in[5];
    const float* b1 = (const float*)d_in[6];
    const float* m1 = (const float*)d_in[7];
    const float* v1 = (const float*)d_in[8];
    const float* w2 = (const float*)d_in[9];
    const float* g2 = (const float*)d_in[10];
    const float* b2 = (const float*)d_in[11];
    const float* m2 = (const float*)d_in[12];
    const float* v2 = (const float*)d_in[13];

    // workspace layout (float units)
    float* ws = (float*)d_ws;
    int* idx = (int*)(ws + 0);              // 40 ints (padded to 64 floats)
    float* w1bs = ws + 64;                  // 4096
    float* ebb = w1bs + 4096;               // 2560
    float* sbg = ebb + 2560;                // 2560
    float* bb1 = sbg + 2560;                // 64
    float* bb2 = bb1 + 64;                  // 64
    unsigned short* wa_bf = (unsigned short*)(bb2 + 64); // 4096 shorts
    unsigned short* wc_bf = wa_bf + 4096;
    unsigned short* w2_bf = wc_bf + 4096;

    float* out_feats = (float*)d_out + (size_t)B_ * N_ * 3;

    // output[0]: fg_xyz passthrough
    hipMemcpyAsync(d_out, d_in[0], (size_t)B_ * N_ * 3 * sizeof(float),
                   hipMemcpyDeviceToDevice, stream);

    fps_kernel<<<B_, 512, 0, stream>>>(bg_xyz, idx);
    prep_w<<<1, 256, 0, stream>>>(w1, g1, b1, m1, v1, w2, g2, b2, m2, v2,
                                  w1bs, bb1, bb2, wa_bf, wc_bf, w2_bf);
    prep_sbg<<<dim3(B_, S_), 64, 0, stream>>>(bg_feat, idx, w1bs, bb1, sbg, ebb);
    fusion_main<<<dim3(N_ / 64, B_), 256, 0, stream>>>(
        fg_feat, wa_bf, wc_bf, w2_bf, bb1, bb2, ebb, sbg, out_feats);
}